// Round 4
// baseline (1087.214 us; speedup 1.0000x reference)
//
#include <hip/hip_runtime.h>
#include <stdint.h>

#define Bb 8
#define Dd 256
#define Ll 4096
#define Kk 4096
#define Nn (Bb * Ll)          // 32768 rows
#define OUT0 (Bb * Dd * Ll)   // 8388608

typedef int    int4v   __attribute__((ext_vector_type(4)));
typedef int    int8v   __attribute__((ext_vector_type(8)));
typedef float  floatx4 __attribute__((ext_vector_type(4)));

#define SCALE1 0x7F7F7F7F     // E8M0 exp=127 -> x1.0 for every 32-elem block

union V8 { int8v v; int4v h[2]; };

// ---------------------------------------------------------------- kernel 1
// normalize codebook rows, scale x16, cast fp8 e4m3, and store in FRAGMENT
// ORDER so the GEMM streams B straight from L2 into MFMA operands with
// fully-coalesced dwordx4 loads (no LDS staging, no barriers):
//   packed int index = g*1024 + ks*512 + c*256 + (l4d*16 + (row&15))*4 + r
//   (g=row>>4 16-col group, ks=K-half, c=16B half, l4d=d-quad, r=dword)
// GEMM lane L of group g reads 16B chunks at g*4096 + ks*2048 + c*1024 + L*16.
// Block 0 zeroes counts + lossacc + done.
__global__ void k_prep(const float* __restrict__ w, unsigned char* __restrict__ wn,
                       int* __restrict__ counts) {
    int blk = blockIdx.x, tid = threadIdx.x;
    if (blk == 0)
        for (int i = tid; i < Kk + 2; i += 256) counts[i] = 0;
    int row  = blk * 4 + (tid >> 6);
    int lane = tid & 63;
    float4 v = ((const float4*)(w + (size_t)row * Dd))[lane];
    float ss = v.x*v.x + v.y*v.y + v.z*v.z + v.w*v.w;
#pragma unroll
    for (int m = 1; m < 64; m <<= 1) ss += __shfl_xor(ss, m, 64);
    float s = 16.0f / fmaxf(sqrtf(ss), 1e-12f);
    int p = __builtin_amdgcn_cvt_pk_fp8_f32(v.x * s, v.y * s, 0, false);
    p     = __builtin_amdgcn_cvt_pk_fp8_f32(v.z * s, v.w * s, p, true);
    // lane covers d0 = lane*4: ks=d0>>7, l4d=(d0>>5)&3, c=(d0>>4)&1, r=(d0>>2)&3
    int g = row >> 4, l15r = row & 15;
    int ks = lane >> 5, l4d = (lane >> 3) & 3, c = (lane >> 2) & 1, r = lane & 3;
    ((int*)wn)[g * 1024 + ks * 512 + c * 256 + (l4d * 16 + l15r) * 4 + r] = p;
}

// ---------------------------------------------------------------- kernel 2
// fused transpose + fp8 cast + full-col argmax GEMM + gather/loss epilogue.
// ROUNDS 1-3 post-mortem: every barrier-synced LDS-staging variant of B pins
// MfmaUtil at 13-17% (= the 14.7us MFMA floor spread over 5-6x the time).
// B is 1MB, L2-resident -> LDS staging is pure overhead. This version
// deletes the B LDS path: k_prep pre-packs B in fragment order; the inner
// loop is 4 coalesced dwordx4 L2 loads + 8 MFMA with a 1-deep register
// prefetch, NO barriers, NO LDS. Waves run free; L2 (~15us) overlaps MFMA
// (~15us) instead of serializing. 512 blocks x 256 thr, 64 rows x 4096 cols;
// 4 waves split cols only (1x B read amplification; wm-dup eliminated).
// XCD swizzle: each XCD owns one batch b (x/out L2 locality), bijective.
__global__ __launch_bounds__(256, 2) void k_gemm_fused(
        const float* __restrict__ x, const unsigned char* __restrict__ Wn,
        const float* __restrict__ w, float* __restrict__ out,
        int* __restrict__ counts) {
    __shared__ __align__(16) unsigned char As[64 * 256];  // 16 KB x-tile fp8
    __shared__ unsigned int red[64][4];
    __shared__ int kidx[64];
    __shared__ float wsum[4];
    __shared__ int lastp;

    float* lossacc = (float*)(counts + Kk);
    int*   done    = counts + Kk + 1;

    int bid = blockIdx.x;
    int bm = ((bid & 7) << 6) | (bid >> 3);   // XCD j -> orig 64j..64j+63
    int tid = threadIdx.x, lane = tid & 63, wv = tid >> 6;
    int l15 = lane & 15, l4 = lane >> 4;

    // ---- fused transpose: x slab [256 d][64 l] f32 -> As[l][d] fp8 (swz)
    int b = bm >> 6, l0 = (bm & 63) * 64;
    const float* xs = x + (size_t)b * Dd * Ll + l0;
    int lg = tid & 15, dgr = tid >> 4;    // 16 l-groups x 16 d-groups
#pragma unroll
    for (int i = 0; i < 4; ++i) {
        int d0 = dgr * 4 + i * 64;
        const float* s0 = xs + (size_t)d0 * Ll + lg * 4;
        float4 f0 = *(const float4*)(s0);
        float4 f1 = *(const float4*)(s0 + Ll);
        float4 f2 = *(const float4*)(s0 + 2 * (size_t)Ll);
        float4 f3 = *(const float4*)(s0 + 3 * (size_t)Ll);
#pragma unroll
        for (int jl = 0; jl < 4; ++jl) {
            float a0 = ((const float*)&f0)[jl], a1 = ((const float*)&f1)[jl];
            float a2 = ((const float*)&f2)[jl], a3 = ((const float*)&f3)[jl];
            int pk = __builtin_amdgcn_cvt_pk_fp8_f32(a0, a1, 0, false);
            pk     = __builtin_amdgcn_cvt_pk_fp8_f32(a2, a3, pk, true);
            int l = lg * 4 + jl;
            *(int*)(As + l * 256 + (((d0 >> 4) ^ (l & 15)) << 4) + (d0 & 15)) = pk;
        }
    }
    __syncthreads();   // As complete

    // ---- A fragments (64 VGPRs): row = fm*16+l15, k = ks*128+l4*32
    int8v af[4][2];
#pragma unroll
    for (int fm = 0; fm < 4; ++fm)
#pragma unroll
        for (int ks = 0; ks < 2; ++ks) {
            int l = fm * 16 + l15;
            int ch = ks * 8 + l4 * 2;
            V8 u;
            u.h[0] = *(const int4v*)(As + l * 256 + ((ch ^ l15) << 4));
            u.h[1] = *(const int4v*)(As + l * 256 + (((ch + 1) ^ l15) << 4));
            af[fm][ks] = u.v;
        }

    unsigned int rk[4][4];
#pragma unroll
    for (int fm = 0; fm < 4; ++fm)
#pragma unroll
        for (int r = 0; r < 4; ++r) rk[fm][r] = 0u;

    // ---- barrier-free main loop: wave wv handles 16-col groups
    // g = it*4+wv, it = 0..63. B fragments streamed from L2 in packed
    // order (4 dwordx4, contiguous 1KB per (g,ks,c)), 1-deep reg prefetch.
    const unsigned char* bp = Wn + (size_t)wv * 4096 + (size_t)lane * 16;
    V8 c0, c1;
    c0.h[0] = *(const int4v*)(bp);
    c0.h[1] = *(const int4v*)(bp + 1024);
    c1.h[0] = *(const int4v*)(bp + 2048);
    c1.h[1] = *(const int4v*)(bp + 3072);

#define VQ_COMPUTE(ITER)                                                      \
    do {                                                                      \
        unsigned int i0 = (unsigned)(((ITER) * 4 + wv) * 16 + l15);           \
        __builtin_amdgcn_s_setprio(1);                                        \
        _Pragma("unroll")                                                     \
        for (int fm = 0; fm < 4; ++fm) {                                      \
            floatx4 a = (floatx4)512.0f;                                      \
            a = __builtin_amdgcn_mfma_scale_f32_16x16x128_f8f6f4(             \
                    af[fm][0], c0.v, a, 0, 0, 0, SCALE1, 0, SCALE1);          \
            a = __builtin_amdgcn_mfma_scale_f32_16x16x128_f8f6f4(             \
                    af[fm][1], c1.v, a, 0, 0, 0, SCALE1, 0, SCALE1);          \
            _Pragma("unroll")                                                 \
            for (int r = 0; r < 4; ++r) {                                     \
                unsigned int k0 = (__float_as_uint(a[r]) & 0xFFFFF000u) | i0; \
                rk[fm][r] = rk[fm][r] > k0 ? rk[fm][r] : k0;                  \
            }                                                                 \
        }                                                                     \
        __builtin_amdgcn_s_setprio(0);                                        \
    } while (0)

#pragma unroll 2
    for (int it = 0; it < 63; ++it) {
        const unsigned char* q = bp + (size_t)(it + 1) * 16384;
        V8 n0, n1;
        n0.h[0] = *(const int4v*)(q);
        n0.h[1] = *(const int4v*)(q + 1024);
        n1.h[0] = *(const int4v*)(q + 2048);
        n1.h[1] = *(const int4v*)(q + 3072);
        VQ_COMPUTE(it);
        c0 = n0; c1 = n1;
    }
    VQ_COMPUTE(63);
#undef VQ_COMPUTE

    // epilogue: key-max across 16 col-lanes, then across 4 wave-strips
#pragma unroll
    for (int fm = 0; fm < 4; ++fm)
#pragma unroll
        for (int r = 0; r < 4; ++r) {
            unsigned int kx = rk[fm][r];
#pragma unroll
            for (int md = 1; md <= 8; md <<= 1) {
                unsigned int o = (unsigned int)__shfl_xor((int)kx, md, 64);
                kx = kx > o ? kx : o;
            }
            if (l15 == 0) red[fm * 16 + l4 * 4 + r][wv] = kx;
        }
    __syncthreads();
    if (tid < 64) {
        unsigned int k0 = red[tid][0], k1 = red[tid][1];
        unsigned int k2 = red[tid][2], k3 = red[tid][3];
        unsigned int kx = k0 > k1 ? k0 : k1;
        kx = kx > k2 ? kx : k2;
        kx = kx > k3 ? kx : k3;
        int ix = (int)(kx & 0xFFFu);
        kidx[tid] = ix;
        atomicAdd(&counts[ix], 1);
    }
    __syncthreads();   // kidx visible to all

    // ---- fused gather + out-write + loss, registers only (no LDS stage).
    // Thread (lg,dgr): l = lg*4..+3, d = dgr*4+i*64+dd. x re-read = same
    // float4s as the transpose (own-XCD L2-warm via batch swizzle); w rows
    // read in contiguous 256B per 16-thread dgr-group (w 4MB, L2/L3).
    float ls = 0.f;
    {
        float* os = out + (size_t)b * Dd * Ll + l0;
        int r0 = lg * 4;
#pragma unroll
        for (int i = 0; i < 4; ++i) {
            int d0 = dgr * 4 + i * 64;
            float4 xv[4];
#pragma unroll
            for (int dd = 0; dd < 4; ++dd)
                xv[dd] = *(const float4*)(xs + (size_t)(d0 + dd) * Ll + lg * 4);
            float4 q4[4];
#pragma unroll
            for (int jl = 0; jl < 4; ++jl)
                q4[jl] = *(const float4*)(w + (size_t)kidx[r0 + jl] * Dd + d0);
#pragma unroll
            for (int dd = 0; dd < 4; ++dd) {
                float4 qq;
                qq.x = ((const float*)&q4[0])[dd];
                qq.y = ((const float*)&q4[1])[dd];
                qq.z = ((const float*)&q4[2])[dd];
                qq.w = ((const float*)&q4[3])[dd];
                float e0 = qq.x - xv[dd].x, e1 = qq.y - xv[dd].y;
                float e2 = qq.z - xv[dd].z, e3 = qq.w - xv[dd].w;
                ls += e0*e0 + e1*e1 + e2*e2 + e3*e3;
                *(float4*)(os + (size_t)(d0 + dd) * Ll + lg * 4) = qq;
            }
        }
    }

#pragma unroll
    for (int m = 1; m < 64; m <<= 1) ls += __shfl_xor(ls, m, 64);
    if (lane == 0) wsum[wv] = ls;
    __syncthreads();
    if (tid == 0) {
        atomicAdd(lossacc, wsum[0] + wsum[1] + wsum[2] + wsum[3]);
        __threadfence();
        lastp = (atomicAdd(done, 1) == 511);
    }
    __syncthreads();
    if (lastp) {                  // all blocks' counts/loss atomics visible
        __threadfence();
        float s = 0.f;
        for (int i = tid; i < Kk; i += 256) {
            float p = (float)counts[i] * (1.0f / Nn);
            s += p * logf(p + 1e-10f);
        }
#pragma unroll
        for (int m = 1; m < 64; m <<= 1) s += __shfl_xor(s, m, 64);
        if (lane == 0) wsum[wv] = s;
        __syncthreads();
        if (tid == 0) {
            out[OUT0]     = lossacc[0] * 1.25f / (float)OUT0;  // q + 0.25*e latent
            out[OUT0 + 1] = expf(-(wsum[0] + wsum[1] + wsum[2] + wsum[3]));
        }
    }
}

// ---------------------------------------------------------------- launch
extern "C" void kernel_launch(void* const* d_in, const int* in_sizes, int n_in,
                              void* d_out, int out_size, void* d_ws, size_t ws_size,
                              hipStream_t stream) {
    const float* x = (const float*)d_in[0];   // [B, D, L]
    const float* w = (const float*)d_in[1];   // [K, D]
    float* out = (float*)d_out;
    char* ws = (char*)d_ws;

    unsigned char* wn     = (unsigned char*)ws;            // 1 MB fp8 (packed)
    int*           counts = (int*)(ws + (1u << 20));       // 16 KB + 8 B

    k_prep      <<<1024, 256, 0, stream>>>(w, wn, counts);
    k_gemm_fused<<<512,  256, 0, stream>>>(x, wn, w, out, counts);
}

// Round 6
// 168.454 us; speedup vs baseline: 6.4541x; 6.4541x over previous
//
#include <hip/hip_runtime.h>
#include <stdint.h>

#define Bb 8
#define Dd 256
#define Ll 4096
#define Kk 4096
#define Nn (Bb * Ll)          // 32768 rows
#define OUT0 (Bb * Dd * Ll)   // 8388608

typedef int    int4v   __attribute__((ext_vector_type(4)));
typedef int    int8v   __attribute__((ext_vector_type(8)));
typedef float  floatx4 __attribute__((ext_vector_type(4)));

#define SCALE1 0x7F7F7F7F     // E8M0 exp=127 -> x1.0 for every 32-elem block

union V8 { int8v v; int4v h[2]; };

__device__ __forceinline__ void async_load16(const void* g, void* l) {
    __builtin_amdgcn_global_load_lds((const __attribute__((address_space(1))) void*)g,
                                     (__attribute__((address_space(3))) void*)l, 16, 0, 0);
}

// ---------------------------------------------------------------- kernel 1
// normalize codebook rows, scale x16, cast fp8 e4m3, row-major wn[k][d].
// Block 0 zeroes counts + lossacc + done.
__global__ void k_prep(const float* __restrict__ w, unsigned char* __restrict__ wn,
                       int* __restrict__ counts) {
    int blk = blockIdx.x, tid = threadIdx.x;
    if (blk == 0)
        for (int i = tid; i < Kk + 2; i += 256) counts[i] = 0;
    int row  = blk * 4 + (tid >> 6);
    int lane = tid & 63;
    float4 v = ((const float4*)(w + (size_t)row * Dd))[lane];
    float ss = v.x*v.x + v.y*v.y + v.z*v.z + v.w*v.w;
#pragma unroll
    for (int m = 1; m < 64; m <<= 1) ss += __shfl_xor(ss, m, 64);
    float s = 16.0f / fmaxf(sqrtf(ss), 1e-12f);
    int p = __builtin_amdgcn_cvt_pk_fp8_f32(v.x * s, v.y * s, 0, false);
    p     = __builtin_amdgcn_cvt_pk_fp8_f32(v.z * s, v.w * s, p, true);
    ((int*)(wn + (size_t)row * Dd))[lane] = p;
}

// ---------------------------------------------------------------- kernel 2
// fused transpose + fp8 cast + full-col argmax GEMM + gather/loss epilogue.
// Barrier-FREE main loop via wave-private B staging (round-5 structure,
// resubmitted after infra failure; waitcnt asm hardened per rule #18).
// R1-R3: all barriered variants pin MfmaUtil at 13-17% (stage+vmcnt+barrier
// lockstep stall). R4: global->reg streaming = GB-scale spill/thrash.
// Here each wave owns a PRIVATE triple-buffered 4KB strip (16 cols x 256B)
// in LDS, staged by global_load_lds and paced only by its own vmcnt
// (per-wave counter -> no cross-wave hazard -> no barrier for 64 tiles).
// Waves drift out of phase; one wave's ds/keypack hides under another's
// MFMA (m114). Wn = 1MB <= L2/XCD so drift can't thrash B.
// 512 blocks x 256 thr: 64 rows x all 4096 cols; wave wv does strips
// g = t*4+wv. XCD swizzle: each XCD owns one batch b; bijective (512%8=0).
__global__ __launch_bounds__(256, 2) void k_gemm_fused(
        const float* __restrict__ x, const unsigned char* __restrict__ Wn,
        const float* __restrict__ w, float* __restrict__ out,
        int* __restrict__ counts) {
    __shared__ __align__(16) unsigned char As[64 * 256];        // 16 KB
    __shared__ __align__(16) unsigned char Bs[4][3][16 * 256];  // 48 KB
    __shared__ unsigned int red[64][4];
    __shared__ int kidx[64];
    __shared__ float wsum[4];
    __shared__ int lastp;

    float* lossacc = (float*)(counts + Kk);
    int*   done    = counts + Kk + 1;

    int bid = blockIdx.x;
    int bm = ((bid & 7) << 6) | (bid >> 3);   // XCD j -> orig 64j..64j+63
    int tid = threadIdx.x, lane = tid & 63, wv = tid >> 6;
    int l15 = lane & 15, l4 = lane >> 4;

    // per-lane DMA maps for one strip (16 rows x 256B, 4 wave-loads):
    // LDS chunk q = j*64+lane holds global chunk (c=q>>4, p=(q&15)^(c&15))
    int goff[4], loff[4];
#pragma unroll
    for (int j = 0; j < 4; ++j) {
        int c = j * 4 + l4;
        goff[j] = c * 256 + ((l15 ^ (c & 15)) << 4);
        loff[j] = j * 1024 + lane * 16;
    }

    // prologue: stage strips t=0,1 into bufs 0,1 (transpose sync drains)
#pragma unroll
    for (int j = 0; j < 4; ++j)
        async_load16(Wn + (size_t)(0 * 4 + wv) * 4096 + goff[j],
                     Bs[wv][0] + loff[j]);
#pragma unroll
    for (int j = 0; j < 4; ++j)
        async_load16(Wn + (size_t)(1 * 4 + wv) * 4096 + goff[j],
                     Bs[wv][1] + loff[j]);

    // ---- fused transpose: x slab [256 d][64 l] f32 -> As[l][d] fp8 (swz)
    int b = bm >> 6, l0 = (bm & 63) * 64;
    const float* xs = x + (size_t)b * Dd * Ll + l0;
    int lg = tid & 15, dgr = tid >> 4;    // 16 l-groups x 16 d-groups
#pragma unroll
    for (int i = 0; i < 4; ++i) {
        int d0 = dgr * 4 + i * 64;
        const float* s0 = xs + (size_t)d0 * Ll + lg * 4;
        float4 f0 = *(const float4*)(s0);
        float4 f1 = *(const float4*)(s0 + Ll);
        float4 f2 = *(const float4*)(s0 + 2 * (size_t)Ll);
        float4 f3 = *(const float4*)(s0 + 3 * (size_t)Ll);
#pragma unroll
        for (int jl = 0; jl < 4; ++jl) {
            float a0 = ((const float*)&f0)[jl], a1 = ((const float*)&f1)[jl];
            float a2 = ((const float*)&f2)[jl], a3 = ((const float*)&f3)[jl];
            int pk = __builtin_amdgcn_cvt_pk_fp8_f32(a0, a1, 0, false);
            pk     = __builtin_amdgcn_cvt_pk_fp8_f32(a2, a3, pk, true);
            int l = lg * 4 + jl;
            *(int*)(As + l * 256 + (((d0 >> 4) ^ (l & 15)) << 4) + (d0 & 15)) = pk;
        }
    }
    __syncthreads();   // As complete (also drains prologue DMA: harmless)

    // ---- A fragments (64 VGPRs): row = fm*16+l15, k = ks*128+l4*32
    int8v af[4][2];
#pragma unroll
    for (int fm = 0; fm < 4; ++fm)
#pragma unroll
        for (int ks = 0; ks < 2; ++ks) {
            int l = fm * 16 + l15;
            int ch = ks * 8 + l4 * 2;
            V8 u;
            u.h[0] = *(const int4v*)(As + l * 256 + ((ch ^ l15) << 4));
            u.h[1] = *(const int4v*)(As + l * 256 + (((ch + 1) ^ l15) << 4));
            af[fm][ks] = u.v;
        }

    unsigned int rk[4][4];
#pragma unroll
    for (int fm = 0; fm < 4; ++fm)
#pragma unroll
        for (int r = 0; r < 4; ++r) rk[fm][r] = 0u;

    // ---- barrier-free main loop: 64 tiles, wave-private staging.
    // top of t: outstanding = strips t, t+1 (4 loads each); vmcnt(4)
    // completes strip t (own-wave loads only -> correct by construction).
    int base0 = l15 * 256;
    for (int t = 0; t < 64; ++t) {
        const unsigned char* p0 = Bs[wv][t % 3];
        unsigned char*       p2 = Bs[wv][(t + 2) % 3];
        if (t == 63) asm volatile("s_waitcnt vmcnt(0)" ::: "memory");
        else         asm volatile("s_waitcnt vmcnt(4)" ::: "memory");
        __builtin_amdgcn_sched_barrier(0);   // rule #18: fence ds_reads below
        if (t < 62) {
            const unsigned char* g = Wn + (size_t)((t + 2) * 4 + wv) * 4096;
#pragma unroll
            for (int j = 0; j < 4; ++j)
                async_load16(g + goff[j], p2 + loff[j]);
        }
        V8 bf0, bf1;
        bf0.h[0] = *(const int4v*)(p0 + base0 + (((l4 * 2 + 0) ^ l15) << 4));
        bf0.h[1] = *(const int4v*)(p0 + base0 + (((l4 * 2 + 1) ^ l15) << 4));
        bf1.h[0] = *(const int4v*)(p0 + base0 + (((8 + l4 * 2 + 0) ^ l15) << 4));
        bf1.h[1] = *(const int4v*)(p0 + base0 + (((8 + l4 * 2 + 1) ^ l15) << 4));
        __builtin_amdgcn_s_setprio(1);
        floatx4 acc[4];
#pragma unroll
        for (int fm = 0; fm < 4; ++fm) {
            floatx4 a = (floatx4)512.0f;      // bias -> positive, int-ordered
            a = __builtin_amdgcn_mfma_scale_f32_16x16x128_f8f6f4(
                    af[fm][0], bf0.v, a, 0, 0, 0, SCALE1, 0, SCALE1);
            a = __builtin_amdgcn_mfma_scale_f32_16x16x128_f8f6f4(
                    af[fm][1], bf1.v, a, 0, 0, 0, SCALE1, 0, SCALE1);
            acc[fm] = a;
        }
        __builtin_amdgcn_s_setprio(0);
        unsigned int i0 = (unsigned)((t * 4 + wv) * 16 + l15);
#pragma unroll
        for (int fm = 0; fm < 4; ++fm)
#pragma unroll
            for (int r = 0; r < 4; ++r) {
                unsigned int k0 = (__float_as_uint(acc[fm][r]) & 0xFFFFF000u) | i0;
                rk[fm][r] = rk[fm][r] > k0 ? rk[fm][r] : k0;
            }
    }

    // epilogue: key-max across 16 col-lanes, then across 4 wave-strips
#pragma unroll
    for (int fm = 0; fm < 4; ++fm)
#pragma unroll
        for (int r = 0; r < 4; ++r) {
            unsigned int kx = rk[fm][r];
#pragma unroll
            for (int md = 1; md <= 8; md <<= 1) {
                unsigned int o = (unsigned int)__shfl_xor((int)kx, md, 64);
                kx = kx > o ? kx : o;
            }
            if (l15 == 0) red[fm * 16 + l4 * 4 + r][wv] = kx;
        }
    __syncthreads();
    if (tid < 64) {
        unsigned int k0 = red[tid][0], k1 = red[tid][1];
        unsigned int k2 = red[tid][2], k3 = red[tid][3];
        unsigned int kx = k0 > k1 ? k0 : k1;
        kx = kx > k2 ? kx : k2;
        kx = kx > k3 ? kx : k3;
        int ix = (int)(kx & 0xFFFu);
        kidx[tid] = ix;
        atomicAdd(&counts[ix], 1);
    }
    __syncthreads();   // kidx visible to all

    // ---- fused gather + out-write + loss, registers only (no LDS stage).
    // Thread (lg,dgr): l = lg*4..+3, d = dgr*4+i*64+dd. x re-read = same
    // float4s as the transpose (own-XCD L2-warm via batch swizzle); w rows
    // read in contiguous 256B per 16-thread dgr-group (w 4MB, L2/L3).
    float ls = 0.f;
    {
        float* os = out + (size_t)b * Dd * Ll + l0;
        int r0 = lg * 4;
#pragma unroll
        for (int i = 0; i < 4; ++i) {
            int d0 = dgr * 4 + i * 64;
            float4 xv[4];
#pragma unroll
            for (int dd = 0; dd < 4; ++dd)
                xv[dd] = *(const float4*)(xs + (size_t)(d0 + dd) * Ll + lg * 4);
            float4 q4[4];
#pragma unroll
            for (int jl = 0; jl < 4; ++jl)
                q4[jl] = *(const float4*)(w + (size_t)kidx[r0 + jl] * Dd + d0);
#pragma unroll
            for (int dd = 0; dd < 4; ++dd) {
                float4 qq;
                qq.x = ((const float*)&q4[0])[dd];
                qq.y = ((const float*)&q4[1])[dd];
                qq.z = ((const float*)&q4[2])[dd];
                qq.w = ((const float*)&q4[3])[dd];
                float e0 = qq.x - xv[dd].x, e1 = qq.y - xv[dd].y;
                float e2 = qq.z - xv[dd].z, e3 = qq.w - xv[dd].w;
                ls += e0*e0 + e1*e1 + e2*e2 + e3*e3;
                *(float4*)(os + (size_t)(d0 + dd) * Ll + lg * 4) = qq;
            }
        }
    }

#pragma unroll
    for (int m = 1; m < 64; m <<= 1) ls += __shfl_xor(ls, m, 64);
    if (lane == 0) wsum[wv] = ls;
    __syncthreads();
    if (tid == 0) {
        atomicAdd(lossacc, wsum[0] + wsum[1] + wsum[2] + wsum[3]);
        __threadfence();
        lastp = (atomicAdd(done, 1) == 511);
    }
    __syncthreads();
    if (lastp) {                  // all blocks' counts/loss atomics visible
        __threadfence();
        float s = 0.f;
        for (int i = tid; i < Kk; i += 256) {
            float p = (float)counts[i] * (1.0f / Nn);
            s += p * logf(p + 1e-10f);
        }
#pragma unroll
        for (int m = 1; m < 64; m <<= 1) s += __shfl_xor(s, m, 64);
        if (lane == 0) wsum[wv] = s;
        __syncthreads();
        if (tid == 0) {
            out[OUT0]     = lossacc[0] * 1.25f / (float)OUT0;  // q + 0.25*e latent
            out[OUT0 + 1] = expf(-(wsum[0] + wsum[1] + wsum[2] + wsum[3]));
        }
    }
}

// ---------------------------------------------------------------- launch
extern "C" void kernel_launch(void* const* d_in, const int* in_sizes, int n_in,
                              void* d_out, int out_size, void* d_ws, size_t ws_size,
                              hipStream_t stream) {
    const float* x = (const float*)d_in[0];   // [B, D, L]
    const float* w = (const float*)d_in[1];   // [K, D]
    float* out = (float*)d_out;
    char* ws = (char*)d_ws;

    unsigned char* wn     = (unsigned char*)ws;            // 1 MB fp8
    int*           counts = (int*)(ws + (1u << 20));       // 16 KB + 8 B

    k_prep      <<<1024, 256, 0, stream>>>(w, wn, counts);
    k_gemm_fused<<<512,  256, 0, stream>>>(x, wn, w, out, counts);
}